// Round 13
// baseline (2429.454 us; speedup 1.0000x reference)
//
#include <hip/hip_runtime.h>

// BiLSTM-CRF, f32-faithful.
// R13: pipelined role-split. Launch Lx: blocks 0-127 run recur(chunk Lx-1)
// with TWO chain-pairs per block (shared gate weights; pair0's IC send
// latency hides under pair1's gemv); blocks 128-255 run xproj(chunk Lx)
// (two bp slices each, R12 bulk-staged body). xg parity double-buffer makes
// concurrent chunks safe; launch boundary orders xproj(c) before recur(c).
// Recur per-pair protocol = R9 exactly (tagged-data agent atomics, ol-LDS,
// coalesced t<512 updates, 2 barriers). R12 lesson reverted: register-direct
// updates broke coalescing (+bank conflicts) — keep R9 geometry.

#define SLEN 512
#define NTAG 9
#define NEGV -10000.0f

typedef float f32x2 __attribute__((ext_vector_type(2)));
typedef float f32x4 __attribute__((ext_vector_type(4)));

__device__ __forceinline__ float qsum(float v){
  int t = __builtin_amdgcn_update_dpp(0, __float_as_int(v), 0xB1, 0xF, 0xF, false);
  v += __int_as_float(t);
  t = __builtin_amdgcn_update_dpp(0, __float_as_int(v), 0x4E, 0xF, 0xF, false);
  return v + __int_as_float(t);
}
__device__ __forceinline__ float rsum16(float v){
  v = qsum(v);
  int t = __builtin_amdgcn_update_dpp(0, __float_as_int(v), 0x124, 0xF, 0xF, false);
  v += __int_as_float(t);
  t = __builtin_amdgcn_update_dpp(0, __float_as_int(v), 0x128, 0xF, 0xF, false);
  return v + __int_as_float(t);
}

#define MAC2(S, WP, HV) { \
  f32x2 _h01{(HV).x,(HV).y}, _h23{(HV).z,(HV).w}; \
  asm("v_pk_fma_f32 %0, %1, %2, %0 op_sel:[0,0,0] op_sel_hi:[0,1,1]" : "+v"(S) : "v"(WP), "v"(_h01)); \
  asm("v_pk_fma_f32 %0, %1, %2, %0 op_sel:[1,0,0] op_sel_hi:[1,1,1]" : "+v"(S) : "v"(WP), "v"(_h23)); }

#define LDW(rr,kq,A,B) { f32x4 v = wp[((rr)*4+(kq))*1024 + t]; A = f32x2{v.x,v.y}; B = f32x2{v.z,v.w}; }

#define DECLW \
  f32x2 w00,w01,w02,w03,w04,w05,w06,w07; \
  f32x2 w10,w11,w12,w13,w14,w15,w16,w17; \
  f32x2 w20,w21,w22,w23,w24,w25,w26,w27; \
  f32x2 w30,w31,w32,w33,w34,w35,w36,w37; \
  LDW(0,0,w00,w01) LDW(0,1,w02,w03) LDW(0,2,w04,w05) LDW(0,3,w06,w07) \
  LDW(1,0,w10,w11) LDW(1,1,w12,w13) LDW(1,2,w14,w15) LDW(1,3,w16,w17) \
  LDW(2,0,w20,w21) LDW(2,1,w22,w23) LDW(2,2,w24,w25) LDW(2,3,w26,w27) \
  LDW(3,0,w30,w31) LDW(3,1,w32,w33) LDW(3,2,w34,w35) LDW(3,3,w36,w37)

#define PINW \
  asm volatile("" : "+v"(w00),"+v"(w01),"+v"(w02),"+v"(w03),"+v"(w04),"+v"(w05),"+v"(w06),"+v"(w07)); \
  asm volatile("" : "+v"(w10),"+v"(w11),"+v"(w12),"+v"(w13),"+v"(w14),"+v"(w15),"+v"(w16),"+v"(w17)); \
  asm volatile("" : "+v"(w20),"+v"(w21),"+v"(w22),"+v"(w23),"+v"(w24),"+v"(w25),"+v"(w26),"+v"(w27)); \
  asm volatile("" : "+v"(w30),"+v"(w31),"+v"(w32),"+v"(w33),"+v"(w34),"+v"(w35),"+v"(w36),"+v"(w37));

#define GCHUNK(c, WA0,WA1, WB0,WB1, WC0,WC1, WD0,WD1) { \
  f32x4 hA = *(const f32x4*)(hb + (c)*8); \
  f32x4 hB = *(const f32x4*)(hb + (c)*8 + 4); \
  MAC2(s0,WA0,hA) MAC2(s0,WA1,hB) \
  MAC2(s1,WB0,hA) MAC2(s1,WB1,hB) \
  MAC2(s2,WC0,hA) MAC2(s2,WC1,hB) \
  MAC2(s3,WD0,hA) MAC2(s3,WD1,hB) }

#define GEMV4x16 \
  f32x2 s0{0.f,0.f}, s1{0.f,0.f}, s2{0.f,0.f}, s3{0.f,0.f}; \
  GCHUNK(0, w00,w01, w10,w11, w20,w21, w30,w31) \
  GCHUNK(1, w02,w03, w12,w13, w22,w23, w32,w33) \
  GCHUNK(2, w04,w05, w14,w15, w24,w25, w34,w35) \
  GCHUNK(3, w06,w07, w16,w17, w26,w27, w36,w37)

union PK { struct { float v; int tg; } s; unsigned long long u; };

// wS[(((role*2+d)*4+g)*16 + rr*4+kq)*4096 + t*4 + e] =
//   W[g*256 + (t>>4)*4 + rr][(t&15)*16 + kq*4 + e]   role0=Wih, role1=Whh
__global__ void prep_k(const float* __restrict__ wihf, const float* __restrict__ whhf,
                       const float* __restrict__ wihr, const float* __restrict__ whhr,
                       float* __restrict__ wS){
  for (int i = blockIdx.x*blockDim.x + threadIdx.x; i < (1<<20); i += gridDim.x*blockDim.x){
    int e=i&3, t=(i>>2)&1023, inst=(i>>12)&15, g=(i>>16)&3, d=(i>>18)&1, role=(i>>19)&1;
    int rr = inst>>2, kq = inst&3;
    int row = g*256 + (t>>4)*4 + rr;
    int k   = (t&15)*16 + kq*4 + e;
    const float* s = role ? (d? whhr : whhf) : (d? wihr : wihf);
    wS[i] = s[row*256 + k];
  }
}

// pair0 gemv+send+ol (uses DECLW names, rg/ks/par/target/g from scope)
#define RECUR_GEMV_SEND(HL, GRP, OLP) { \
  const float* hb = (HL) + ks*36; \
  GEMV4x16 \
  float r0a=rsum16(s0.x), r0b=rsum16(s0.y); \
  float r1a=rsum16(s1.x), r1b=rsum16(s1.y); \
  float r2a=rsum16(s2.x), r2b=rsum16(s2.y); \
  float r3a=rsum16(s3.x), r3b=rsum16(s3.y); \
  if (ks < 4){ \
    float ra = (ks==0)?r0a:(ks==1)?r1a:(ks==2)?r2a:r3a; \
    float rb = (ks==0)?r0b:(ks==1)?r1b:(ks==2)?r2b:r3b; \
    int j = rg*4 + ks; \
    (OLP)[j] = ra; (OLP)[256 + j] = rb; \
    PK pa; pa.s.v = ra; pa.s.tg = target; \
    PK pb; pb.s.v = rb; pb.s.tg = target; \
    unsigned long long* sb = send + ((((long)(par*64+(GRP))*4 + g)*2)*256) + j; \
    __hip_atomic_store(sb,       pa.u, __ATOMIC_RELAXED, __HIP_MEMORY_SCOPE_AGENT); \
    __hip_atomic_store(sb + 256, pb.u, __ATOMIC_RELAXED, __HIP_MEMORY_SCOPE_AGENT); \
  } }

#define RECUR_UPD(GRP, OLP, HLW, HPV, CST, X0,X1,X2,X3, MLP, BGT) { \
  const unsigned long long* rb_ = send + (long)(par*64+(GRP))*4*2*256 + b2*256 + j2; \
  PK u1,u2,u3; \
  u1.u = __hip_atomic_load(rb_ + (long)g1*512,  __ATOMIC_RELAXED, __HIP_MEMORY_SCOPE_AGENT); \
  u2.u = __hip_atomic_load(rb_ + (long)g2c*512, __ATOMIC_RELAXED, __HIP_MEMORY_SCOPE_AGENT); \
  u3.u = __hip_atomic_load(rb_ + (long)g3*512,  __ATOMIC_RELAXED, __HIP_MEMORY_SCOPE_AGENT); \
  int cnt = 0; \
  while (u1.s.tg < target || u2.s.tg < target || u3.s.tg < target){ \
    if (u1.s.tg < target) u1.u = __hip_atomic_load(rb_ + (long)g1*512,  __ATOMIC_RELAXED, __HIP_MEMORY_SCOPE_AGENT); \
    if (u2.s.tg < target) u2.u = __hip_atomic_load(rb_ + (long)g2c*512, __ATOMIC_RELAXED, __HIP_MEMORY_SCOPE_AGENT); \
    if (u3.s.tg < target) u3.u = __hip_atomic_load(rb_ + (long)g3*512,  __ATOMIC_RELAXED, __HIP_MEMORY_SCOPE_AGENT); \
    if (++cnt > (1<<15)) break; \
  } \
  float vo = (OLP)[b2*256 + j2]; \
  float a0,a1,a2,a3; \
  if      (g==0){ a0=vo; a1=u1.s.v; a2=u2.s.v; a3=u3.s.v; } \
  else if (g==1){ a1=vo; a2=u1.s.v; a3=u2.s.v; a0=u3.s.v; } \
  else if (g==2){ a2=vo; a3=u1.s.v; a0=u2.s.v; a1=u3.s.v; } \
  else          { a3=vo; a0=u1.s.v; a1=u2.s.v; a2=u3.s.v; } \
  float pi=a0+(X0), pf=a1+(X1), pg_=a2+(X2), po=a3+(X3); \
  float ii=1.f/(1.f+expf(-pi)), ff=1.f/(1.f+expf(-pf)); \
  float gv=tanhf(pg_), oo=1.f/(1.f+expf(-po)); \
  float cn = ff*(CST) + ii*gv; \
  float hn = oo*tanhf(cn); \
  if ((MLP)[b2*Sc+sp] != 0){ (CST)=cn; (HPV)=hn; } \
  (HLW)[(j2>>4)*36 + (j2&15)*2 + b2] = (HPV); \
  if (g == 0){ \
    int sg_ = d ? (SLEN-1-stepg) : stepg; \
    hs[((long)sg_*64 + (BGT))*512 + d*256 + j2] = (HPV); \
  } }

// Fused pipeline kernel. Launch Lx (0..C):
//   bid <  128 : recur role, chunk Lx-1, TWO chain-pairs/block
//   bid >= 128 : xproj role, chunk Lx, two bp slices/block
__global__ __launch_bounds__(1024)
__attribute__((amdgpu_waves_per_eu(4,4)))
void main_k(
    int Lx, int C, int Sc,
    const int* __restrict__ ids, const float* __restrict__ embed,
    const float* __restrict__ wS,
    const float* __restrict__ bias_f, const float* __restrict__ bias_r,
    float* __restrict__ xg, long xg_par_str,
    float* __restrict__ hs,
    float* __restrict__ st_h, float* __restrict__ st_c,
    unsigned long long* __restrict__ send)
{
  __shared__ __align__(16) float smem[64*576];   // 147456B (xbig / recur carve)
  __shared__ int ids_l[1024];
  const int t = threadIdx.x;
  const int bid = blockIdx.x;

  if (bid >= 128){
    // ================= xproj role =================
    const int cx = Lx;
    if (cx >= C) return;
    const int x = bid - 128;
    const int bq = x & 15, g = (x>>4)&3, d = x>>6;
    const int rg = t>>4, ks = t&15;
    const int e = ks&3, bu = (ks>>2)&1;
    const f32x4* wp = (const f32x4*)(wS + (long)((d*4+g)*16)*4096);
    DECLW
    PINW
    const float bbr = (d ? bias_r : bias_f)[g*256 + rg*4 + e];
    float* xgb = xg + (long)(cx&1)*xg_par_str;
    float (*xbig)[576] = (float(*)[576])smem;
    const int SH = (Sc < 64) ? Sc : 64;

    for (int pp=0; pp<2; pp++){
      const int bp = bq*2 + pp;
      for (int i=t; i<2*Sc; i+=1024){
        int b = (i>=Sc) ? 1 : 0, sp = i - b*Sc;
        int sg = d ? (SLEN-1-(cx*Sc+sp)) : (cx*Sc+sp);
        ids_l[i] = ids[(bp*2+b)*SLEN + sg];
      }
      for (int sp0=0; sp0<Sc; sp0+=SH){
        __syncthreads();                          // prior reads (+ids writes) done
        for (int c = t; c < SH*128; c += 1024){   // c = ss*128 + b*64 + kk
          int ss = c>>7, b = (c>>6)&1, kk = c&63;
          int sp = sp0 + ss;
          f32x4 v = ((const f32x4*)embed)[(long)ids_l[b*Sc+sp]*64 + kk];
          float* xb = &xbig[ss][(kk>>2)*36 + (kk&3)*8 + b];
          xb[0] = v.x; xb[2] = v.y; xb[4] = v.z; xb[6] = v.w;
        }
        __syncthreads();
        for (int sp=sp0; sp<sp0+SH; sp++){
          const float* hb = &xbig[sp-sp0][ks*36];
          GEMV4x16
          float r0a = rsum16(s0.x), r0b = rsum16(s0.y);
          float r1a = rsum16(s1.x), r1b = rsum16(s1.y);
          float r2a = rsum16(s2.x), r2b = rsum16(s2.y);
          float r3a = rsum16(s3.x), r3b = rsum16(s3.y);
          if (ks < 8){
            float va = (e==0)?r0a:(e==1)?r1a:(e==2)?r2a:r3a;
            float vb = (e==0)?r0b:(e==1)?r1b:(e==2)?r2b:r3b;
            long base = ((long)(d*Sc+sp)*64 + (bp*2+bu))*1024 + g*256 + rg*4 + e;
            xgb[base] = (bu ? vb : va) + bbr;
          }
        }
      }
      __syncthreads();                            // xbig reads done before next pp
    }
    return;
  }

  // ================= recur role =================
  const int cr = Lx - 1;
  if (cr < 0) return;
  const int g = (bid>>3)&3;
  const int grq = (bid&7) | ((bid>>5)<<3);        // 0..31
  const int d = grq>>4, bq = grq&15;
  const int rg = t>>4, ks = t&15;
  const int grp0 = d*32 + bq*2, grp1 = grp0 + 1;
  const int g1 = (g+1)&3, g2c = (g+2)&3, g3 = (g+3)&3;

  const f32x4* wp = (const f32x4*)(wS + (long)(((2+d)*4+g)*16)*4096);
  DECLW
  PINW

  float* hl0 = smem;                               // 576
  float* hl1 = smem + 576;                         // 576
  float* ol  = smem + 1152;                        // [2 pair][2 b][256] = 1024
  int*   ml  = (int*)(smem + 2176);                // [2 pair][2 b][Sc] <= 2048

  for (int i=t; i<4*Sc; i+=1024){
    int pp = (i >= 2*Sc) ? 1 : 0;
    int ib = i - pp*2*Sc;
    int b = (ib>=Sc) ? 1 : 0, sp = ib - b*Sc;
    int sg = d ? (SLEN-1-(cr*Sc+sp)) : (cr*Sc+sp);
    ml[i] = ids[(bq*4 + pp*2 + b)*SLEN + sg];
  }
  const int j2 = t&255, b2 = t>>8;                 // update mapping (t<512)
  float hpv0=0.f, cst0=0.f, hpv1=0.f, cst1=0.f;
  if (t < 512){
    int bg0 = bq*4 + b2, bg1 = bq*4 + 2 + b2;
    hpv0 = st_h[(d*64+bg0)*256 + j2]; cst0 = st_c[(d*64+bg0)*256 + j2];
    hpv1 = st_h[(d*64+bg1)*256 + j2]; cst1 = st_c[(d*64+bg1)*256 + j2];
    hl0[(j2>>4)*36 + (j2&15)*2 + b2] = hpv0;
    hl1[(j2>>4)*36 + (j2&15)*2 + b2] = hpv1;
  }
  __syncthreads();
  const float* xgb = xg + (long)(cr&1)*xg_par_str;

  for (int sp=0; sp<Sc; sp++){
    const int stepg = cr*Sc + sp;
    const int par = stepg & 1;
    const int target = stepg + 1;
    float x00=0,x01=0,x02=0,x03=0;
    if (t < 512){
      const float* xr = xgb + ((long)(d*Sc+sp)*64 + (bq*4+b2))*1024 + j2;
      x00 = xr[0]; x01 = xr[256]; x02 = xr[512]; x03 = xr[768];
    }
    RECUR_GEMV_SEND(hl0, grp0, ol)                 // pair0: sends propagate...
    RECUR_GEMV_SEND(hl1, grp1, (ol+512))           // ...under pair1's gemv
    __syncthreads();                               // ol visible; hl reads done
    if (t < 512){
      RECUR_UPD(grp0, ol,       hl0, hpv0, cst0, x00,x01,x02,x03, ml,        (bq*4+b2))
      float x10,x11,x12,x13;
      {
        const float* xr = xgb + ((long)(d*Sc+sp)*64 + (bq*4+2+b2))*1024 + j2;
        x10 = xr[0]; x11 = xr[256]; x12 = xr[512]; x13 = xr[768];
      }
      RECUR_UPD(grp1, (ol+512), hl1, hpv1, cst1, x10,x11,x12,x13, (ml+2*Sc), (bq*4+2+b2))
    }
    __syncthreads();                               // hl ready for next gemv
  }
  if (t < 512){
    int bg0 = bq*4 + b2, bg1 = bq*4 + 2 + b2;
    st_h[(d*64+bg0)*256 + j2] = hpv0; st_c[(d*64+bg0)*256 + j2] = cst0;
    st_h[(d*64+bg1)*256 + j2] = hpv1; st_c[(d*64+bg1)*256 + j2] = cst1;
  }
}

__global__ __launch_bounds__(576) void feats_k(
    const float* __restrict__ hs, const float* __restrict__ wout,
    float* __restrict__ feats)
{
  __shared__ __align__(16) float hlds[64*512];
  __shared__ __align__(16) float wl[NTAG*512];
  const int s = blockIdx.x, t = threadIdx.x;
  for (int i = t; i < 64*512/4; i += 576)
    ((f32x4*)hlds)[i] = ((const f32x4*)(hs + (long)s*64*512))[i];
  for (int i = t; i < NTAG*512/4; i += 576)
    ((f32x4*)wl)[i] = ((const f32x4*)wout)[i];
  __syncthreads();
  int b = t / 9, tag = t - b*9;
  float acc = 0.f;
  const float* hb = hlds + b*512;
  const float* wb = wl + tag*512;
  for (int k=0; k<512; k+=4){
    f32x4 h4 = *(const f32x4*)(hb+k);
    f32x4 w4 = *(const f32x4*)(wb+k);
    acc += h4.x*w4.x + h4.y*w4.y + h4.z*w4.z + h4.w*w4.w;
  }
  feats[((long)s*64 + b)*9 + tag] = acc;
}

__global__ __launch_bounds__(64) void viterbi_k(
    const int* __restrict__ ids, const float* __restrict__ feats,
    const float* __restrict__ bout, const float* __restrict__ trans,
    int* __restrict__ outp)
{
  __shared__ float fl[SLEN*NTAG + 64];
  __shared__ unsigned char bps[SLEN*NTAG];
  __shared__ unsigned char mk[SLEN];
  const int b = blockIdx.x, lane = threadIdx.x;
  for (int i=lane; i<SLEN; i+=64) mk[i] = (ids[b*SLEN+i] != 0) ? 1 : 0;
  for (int i=lane; i<SLEN*NTAG; i+=64){
    int s = i/9; int t = i - s*9;
    fl[i] = feats[((long)s*64+b)*9 + t] + bout[t];
  }
  fl[SLEN*NTAG + lane] = 0.f;
  __syncthreads();

  float Tc[9], v[9], vown;
  #pragma unroll
  for (int i=0;i<9;i++) Tc[i] = (lane<9)? trans[i*9 + lane] : 0.f;
  #pragma unroll
  for (int i=0;i<9;i++) v[i] = (i==0)?0.f:NEGV;
  vown = (lane==0)?0.f:NEGV;

  for (int s=0;s<SLEN;s++){
    float best = v[0] + Tc[0]; int bi = 0;
    #pragma unroll
    for (int i=1;i<9;i++){
      float sc = v[i] + Tc[i];
      if (sc > best){ best = sc; bi = i; }       // first-max tie-break
    }
    float nv = best + fl[s*9 + lane];
    bool m = mk[s] != 0;
    if (m && lane<9) vown = nv;
    if (lane < 9) bps[s*9+lane] = (unsigned char)bi;
    #pragma unroll
    for (int i=0;i<9;i++) v[i] = __shfl(vown, i);
  }
  if (lane == 0){
    float best = v[0]; int tag = 0;
    #pragma unroll
    for (int i=1;i<9;i++) if (v[i] > best){ best=v[i]; tag=i; }
    outp[b*SLEN + SLEN-1] = tag;
    for (int t=SLEN-1; t>=1; t--){
      int pv = bps[t*9 + tag];
      if (!mk[t]) pv = 0;
      outp[b*SLEN + t-1] = pv;
      tag = pv;
    }
  }
}

extern "C" void kernel_launch(void* const* d_in, const int* in_sizes, int n_in,
                              void* d_out, int out_size, void* d_ws, size_t ws_size,
                              hipStream_t stream){
  (void)in_sizes; (void)n_in; (void)out_size;
  const int*   ids   = (const int*)  d_in[0];
  const float* embed = (const float*)d_in[2];
  const float* Wih_f = (const float*)d_in[3];
  const float* Whh_f = (const float*)d_in[4];
  const float* b_f   = (const float*)d_in[5];
  const float* Wih_r = (const float*)d_in[6];
  const float* Whh_r = (const float*)d_in[7];
  const float* b_r   = (const float*)d_in[8];
  const float* Wout  = (const float*)d_in[9];
  const float* bout  = (const float*)d_in[10];
  const float* trans = (const float*)d_in[11];

  float* fw = (float*)d_ws;
  size_t off = 0;
  float* wS    = fw + off; off += 1048576;     // 4 MB swizzled Wih+Whh
  unsigned long long* send = (unsigned long long*)(fw + off); off += 524288; // 2 MB tagged
  float* st_h  = fw + off; off += 32768;
  float* st_c  = fw + off; off += 32768;
  float* hs    = fw + off; off += 16777216;    // 64 MB [512][64][512]
  float* featb = fw + off; off += 294912;      // [512][64][9]
  float* xg    = fw + off;
  size_t fixedB = off*4;

  const int cands[7] = {512,256,128,64,32,16,8};
  int Sc = 8;
  for (int ci=0; ci<7; ci++){
    size_t need = fixedB + (size_t)cands[ci]*262144*4;  // xg = 2par*2d*Sc*64*1024 f32
    if (need <= ws_size){ Sc = cands[ci]; break; }
  }
  const long xg_par_str = (long)Sc*131072;
  const int C = SLEN / Sc;

  hipMemsetAsync(send, 0, 524288*4, stream);   // tags must not survive replays
  hipMemsetAsync(st_h, 0, 2*32768*4, stream);  // st_h + st_c contiguous
  prep_k<<<1024,256,0,stream>>>(Wih_f, Whh_f, Wih_r, Whh_r, wS);
  for (int Lx=0; Lx<=C; Lx++){
    main_k<<<256,1024,0,stream>>>(Lx, C, Sc, ids, embed, wS, b_f, b_r,
                                  xg, xg_par_str, hs, st_h, st_c, send);
  }
  feats_k<<<512,576,0,stream>>>(hs, Wout, featb);
  viterbi_k<<<64,64,0,stream>>>(ids, featb, bout, trans, (int*)d_out);
}

// Round 14
// 1841.450 us; speedup vs baseline: 1.3193x; 1.3193x over previous
//
#include <hip/hip_runtime.h>

// BiLSTM-CRF, f32-faithful.
// R14 = R9 (best measured: 1989us) + two isolated wins:
//  (1) xproj bulk-staged (R12's proven form): 64 steps of x staged in 147KB
//      LDS, barrier-free inner loop (2 barriers/64 steps vs 2/step).
//  (2) fast sigmoid/tanh in recur update via v_exp_f32+v_rcp_f32 (~22 inst
//      vs ~84 libm; ~1e-7 abs error, same class as f32 reorder noise).
// R12/R13 lessons: 1-barrier geometry breaks xg coalescing (+75us); fused
// role-split pipeline loses (2-pair recur 540 > 321+150 serial; reg wall
// forbids co-residency). Recur sync/geometry stays exactly R9.

#define SLEN 512
#define NTAG 9
#define NEGV -10000.0f

typedef float f32x2 __attribute__((ext_vector_type(2)));
typedef float f32x4 __attribute__((ext_vector_type(4)));

__device__ __forceinline__ float qsum(float v){
  int t = __builtin_amdgcn_update_dpp(0, __float_as_int(v), 0xB1, 0xF, 0xF, false);
  v += __int_as_float(t);
  t = __builtin_amdgcn_update_dpp(0, __float_as_int(v), 0x4E, 0xF, 0xF, false);
  return v + __int_as_float(t);
}
__device__ __forceinline__ float rsum16(float v){
  v = qsum(v);
  int t = __builtin_amdgcn_update_dpp(0, __float_as_int(v), 0x124, 0xF, 0xF, false);
  v += __int_as_float(t);
  t = __builtin_amdgcn_update_dpp(0, __float_as_int(v), 0x128, 0xF, 0xF, false);
  return v + __int_as_float(t);
}

// fast transcendentals: v_exp_f32 (2^x) + v_rcp_f32, ~1ulp each.
__device__ __forceinline__ float fexp2(float x){
  float r; asm("v_exp_f32 %0, %1" : "=v"(r) : "v"(x)); return r;
}
__device__ __forceinline__ float frcp(float x){
  float r; asm("v_rcp_f32 %0, %1" : "=v"(r) : "v"(x)); return r;
}
__device__ __forceinline__ float fsigm(float x){          // 1/(1+e^-x)
  return frcp(1.0f + fexp2(-1.4426950408889634f * x));
}
__device__ __forceinline__ float ftanh(float x){          // 2*sigm(2x)-1
  return fmaf(2.0f, frcp(1.0f + fexp2(-2.8853900817779268f * x)), -1.0f);
}

#define MAC2(S, WP, HV) { \
  f32x2 _h01{(HV).x,(HV).y}, _h23{(HV).z,(HV).w}; \
  asm("v_pk_fma_f32 %0, %1, %2, %0 op_sel:[0,0,0] op_sel_hi:[0,1,1]" : "+v"(S) : "v"(WP), "v"(_h01)); \
  asm("v_pk_fma_f32 %0, %1, %2, %0 op_sel:[1,0,0] op_sel_hi:[1,1,1]" : "+v"(S) : "v"(WP), "v"(_h23)); }

#define LDW(rr,kq,A,B) { f32x4 v = wp[((rr)*4+(kq))*1024 + t]; A = f32x2{v.x,v.y}; B = f32x2{v.z,v.w}; }

#define DECLW \
  f32x2 w00,w01,w02,w03,w04,w05,w06,w07; \
  f32x2 w10,w11,w12,w13,w14,w15,w16,w17; \
  f32x2 w20,w21,w22,w23,w24,w25,w26,w27; \
  f32x2 w30,w31,w32,w33,w34,w35,w36,w37; \
  LDW(0,0,w00,w01) LDW(0,1,w02,w03) LDW(0,2,w04,w05) LDW(0,3,w06,w07) \
  LDW(1,0,w10,w11) LDW(1,1,w12,w13) LDW(1,2,w14,w15) LDW(1,3,w16,w17) \
  LDW(2,0,w20,w21) LDW(2,1,w22,w23) LDW(2,2,w24,w25) LDW(2,3,w26,w27) \
  LDW(3,0,w30,w31) LDW(3,1,w32,w33) LDW(3,2,w34,w35) LDW(3,3,w36,w37)

#define PINW \
  asm volatile("" : "+v"(w00),"+v"(w01),"+v"(w02),"+v"(w03),"+v"(w04),"+v"(w05),"+v"(w06),"+v"(w07)); \
  asm volatile("" : "+v"(w10),"+v"(w11),"+v"(w12),"+v"(w13),"+v"(w14),"+v"(w15),"+v"(w16),"+v"(w17)); \
  asm volatile("" : "+v"(w20),"+v"(w21),"+v"(w22),"+v"(w23),"+v"(w24),"+v"(w25),"+v"(w26),"+v"(w27)); \
  asm volatile("" : "+v"(w30),"+v"(w31),"+v"(w32),"+v"(w33),"+v"(w34),"+v"(w35),"+v"(w36),"+v"(w37));

#define GCHUNK(c, WA0,WA1, WB0,WB1, WC0,WC1, WD0,WD1) { \
  f32x4 hA = *(const f32x4*)(hb + (c)*8); \
  f32x4 hB = *(const f32x4*)(hb + (c)*8 + 4); \
  MAC2(s0,WA0,hA) MAC2(s0,WA1,hB) \
  MAC2(s1,WB0,hA) MAC2(s1,WB1,hB) \
  MAC2(s2,WC0,hA) MAC2(s2,WC1,hB) \
  MAC2(s3,WD0,hA) MAC2(s3,WD1,hB) }

#define GEMV4x16 \
  f32x2 s0{0.f,0.f}, s1{0.f,0.f}, s2{0.f,0.f}, s3{0.f,0.f}; \
  GCHUNK(0, w00,w01, w10,w11, w20,w21, w30,w31) \
  GCHUNK(1, w02,w03, w12,w13, w22,w23, w32,w33) \
  GCHUNK(2, w04,w05, w14,w15, w24,w25, w34,w35) \
  GCHUNK(3, w06,w07, w16,w17, w26,w27, w36,w37)

union PK { struct { float v; int tg; } s; unsigned long long u; };

// wS[(((role*2+d)*4+g)*16 + rr*4+kq)*4096 + t*4 + e] =
//   W[g*256 + (t>>4)*4 + rr][(t&15)*16 + kq*4 + e]   role0=Wih, role1=Whh
__global__ void prep_k(const float* __restrict__ wihf, const float* __restrict__ whhf,
                       const float* __restrict__ wihr, const float* __restrict__ whhr,
                       float* __restrict__ wS){
  for (int i = blockIdx.x*blockDim.x + threadIdx.x; i < (1<<20); i += gridDim.x*blockDim.x){
    int e=i&3, t=(i>>2)&1023, inst=(i>>12)&15, g=(i>>16)&3, d=(i>>18)&1, role=(i>>19)&1;
    int rr = inst>>2, kq = inst&3;
    int row = g*256 + (t>>4)*4 + rr;
    int k   = (t&15)*16 + kq*4 + e;
    const float* s = role ? (d? whhr : whhf) : (d? wihr : wihf);
    wS[i] = s[row*256 + k];
  }
}

// xproj (R12 bulk-staged): block (d,g,bp). Stage SH=min(64,Sc) steps x 2
// batches of x into LDS, then barrier-free inner loop. Lane ks=e+4b (ks<8)
// stores row rg*4+e, batch b register-direct.
__global__ __launch_bounds__(1024)
__attribute__((amdgpu_waves_per_eu(4,4)))
void xproj_k(
    int c0, int Sc,
    const int* __restrict__ ids, const float* __restrict__ embed,
    const float* __restrict__ wS,
    const float* __restrict__ bias_f, const float* __restrict__ bias_r,
    float* __restrict__ xg, long xg_par_str)
{
  __shared__ __align__(16) float xbig[64][576];   // 147KB
  __shared__ int ids_l[1024];
  const int t = threadIdx.x;
  const int bid = blockIdx.x;
  const int bp = bid & 31, g = (bid>>5)&3, d = bid>>7;
  const int rg = t>>4, ks = t&15;
  const int e = ks&3, bu = (ks>>2)&1;

  const f32x4* wp = (const f32x4*)(wS + (long)((d*4+g)*16)*4096);
  DECLW
  PINW
  const float bbr = (d ? bias_r : bias_f)[g*256 + rg*4 + e];

  for (int i=t; i<2*Sc; i+=1024){
    int b = (i>=Sc) ? 1 : 0, sp = i - b*Sc;
    int sg = d ? (SLEN-1-(c0*Sc+sp)) : (c0*Sc+sp);
    ids_l[i] = ids[(bp*2+b)*SLEN + sg];
  }
  const int SH = (Sc < 64) ? Sc : 64;
  float* xgb = xg + (long)(c0&1)*xg_par_str;

  for (int sp0=0; sp0<Sc; sp0+=SH){
    __syncthreads();                              // prior reads (+ids writes) done
    for (int c = t; c < SH*128; c += 1024){       // c = ss*128 + b*64 + kk
      int ss = c>>7, b = (c>>6)&1, kk = c&63;
      int sp = sp0 + ss;
      f32x4 v = ((const f32x4*)embed)[(long)ids_l[b*Sc+sp]*64 + kk];
      float* xb = &xbig[ss][(kk>>2)*36 + (kk&3)*8 + b];
      xb[0] = v.x; xb[2] = v.y; xb[4] = v.z; xb[6] = v.w;
    }
    __syncthreads();
    for (int sp=sp0; sp<sp0+SH; sp++){
      const float* hb = &xbig[sp-sp0][ks*36];
      GEMV4x16
      float r0a = rsum16(s0.x), r0b = rsum16(s0.y);
      float r1a = rsum16(s1.x), r1b = rsum16(s1.y);
      float r2a = rsum16(s2.x), r2b = rsum16(s2.y);
      float r3a = rsum16(s3.x), r3b = rsum16(s3.y);
      if (ks < 8){
        float va = (e==0)?r0a:(e==1)?r1a:(e==2)?r2a:r3a;
        float vb = (e==0)?r0b:(e==1)?r1b:(e==2)?r2b:r3b;
        long base = ((long)(d*Sc+sp)*64 + (bp*2+bu))*1024 + g*256 + rg*4 + e;
        xgb[base] = (bu ? vb : va) + bbr;
      }
    }
  }
}

// recur (R9 exactly + fast transcendentals): blockIdx bits [2:0]=grp_lo,
// [4:3]=g, [7:5]=grp_hi. Tagged-data sync, ol-LDS, coalesced t<512 updates.
__global__ __launch_bounds__(1024)
__attribute__((amdgpu_waves_per_eu(4,4)))
void recur_k(
    int c0, int Sc,
    const int* __restrict__ ids,
    const float* __restrict__ wS,
    const float* __restrict__ xg, long xg_par_str,
    float* __restrict__ hs,
    float* __restrict__ st_h, float* __restrict__ st_c,
    unsigned long long* __restrict__ send)
{
  __shared__ __align__(16) float hl2[576];
  __shared__ float ol[2][256];
  __shared__ int ml[1024];
  const int t = threadIdx.x;
  const int bid = blockIdx.x;
  const int g = (bid>>3)&3;
  const int grp = (bid&7) | ((bid>>5)<<3);
  const int d = grp>>5, bp = grp&31;
  const int rg = t>>4, ks = t&15;

  const f32x4* wp = (const f32x4*)(wS + (long)(((2+d)*4+g)*16)*4096);
  DECLW
  PINW

  for (int i=t; i<2*Sc; i+=1024){
    int b = (i>=Sc) ? 1 : 0, sp = i - b*Sc;
    int sg = d ? (SLEN-1-(c0*Sc+sp)) : (c0*Sc+sp);
    ml[i] = ids[(bp*2+b)*SLEN + sg];
  }
  float cst = 0.f, hpv = 0.f;
  const int j2 = t&255, b2 = t>>8;               // update mapping (t<512)
  if (t < 512){
    int bg = bp*2 + b2;
    hpv = st_h[(d*64+bg)*256 + j2];
    cst = st_c[(d*64+bg)*256 + j2];
    hl2[(j2>>4)*36 + (j2&15)*2 + b2] = hpv;
  }
  __syncthreads();
  const float* xgb = xg + (long)(c0&1)*xg_par_str;
  const float* hb = hl2 + ks*36;
  const int g1 = (g+1)&3, g2c = (g+2)&3, g3 = (g+3)&3;

  for (int sp=0; sp<Sc; sp++){
    const int stepg = c0*Sc + sp;
    const int par = stepg & 1;
    const int target = stepg + 1;
    float x0=0,x1=0,x2=0,x3=0;
    if (t < 512){
      const float* xr = xgb + ((long)(d*Sc+sp)*64 + (bp*2+b2))*1024 + j2;
      x0 = xr[0]; x1 = xr[256]; x2 = xr[512]; x3 = xr[768];
    }
    GEMV4x16
    float r0a = rsum16(s0.x), r0b = rsum16(s0.y);
    float r1a = rsum16(s1.x), r1b = rsum16(s1.y);
    float r2a = rsum16(s2.x), r2b = rsum16(s2.y);
    float r3a = rsum16(s3.x), r3b = rsum16(s3.y);
    if (ks < 4){
      float ra = (ks==0)?r0a:(ks==1)?r1a:(ks==2)?r2a:r3a;
      float rb = (ks==0)?r0b:(ks==1)?r1b:(ks==2)?r2b:r3b;
      int j = rg*4 + ks;
      ol[0][j] = ra; ol[1][j] = rb;
      PK pa; pa.s.v = ra; pa.s.tg = target;
      PK pb; pb.s.v = rb; pb.s.tg = target;
      unsigned long long* sb = send + ((((long)(par*64+grp)*4 + g)*2)*256) + j;
      __hip_atomic_store(sb,       pa.u, __ATOMIC_RELAXED, __HIP_MEMORY_SCOPE_AGENT);
      __hip_atomic_store(sb + 256, pb.u, __ATOMIC_RELAXED, __HIP_MEMORY_SCOPE_AGENT);
    }
    __syncthreads();                             // ol visible; hl2 reads done
    if (t < 512){
      const unsigned long long* rbase =
          send + (long)(par*64+grp)*4*2*256 + b2*256 + j2;
      PK u1, u2, u3;
      u1.u = __hip_atomic_load(rbase + (long)g1*512,  __ATOMIC_RELAXED, __HIP_MEMORY_SCOPE_AGENT);
      u2.u = __hip_atomic_load(rbase + (long)g2c*512, __ATOMIC_RELAXED, __HIP_MEMORY_SCOPE_AGENT);
      u3.u = __hip_atomic_load(rbase + (long)g3*512,  __ATOMIC_RELAXED, __HIP_MEMORY_SCOPE_AGENT);
      int cnt = 0;
      while (u1.s.tg < target || u2.s.tg < target || u3.s.tg < target){
        if (u1.s.tg < target) u1.u = __hip_atomic_load(rbase + (long)g1*512,  __ATOMIC_RELAXED, __HIP_MEMORY_SCOPE_AGENT);
        if (u2.s.tg < target) u2.u = __hip_atomic_load(rbase + (long)g2c*512, __ATOMIC_RELAXED, __HIP_MEMORY_SCOPE_AGENT);
        if (u3.s.tg < target) u3.u = __hip_atomic_load(rbase + (long)g3*512,  __ATOMIC_RELAXED, __HIP_MEMORY_SCOPE_AGENT);
        if (++cnt > (1<<15)) break;
      }
      float vo = ol[b2][j2];
      float a0,a1,a2,a3;                         // gates 0..3 (uniform branch on g)
      if      (g==0){ a0=vo;     a1=u1.s.v; a2=u2.s.v; a3=u3.s.v; }
      else if (g==1){ a1=vo;     a2=u1.s.v; a3=u2.s.v; a0=u3.s.v; }
      else if (g==2){ a2=vo;     a3=u1.s.v; a0=u2.s.v; a1=u3.s.v; }
      else          { a3=vo;     a0=u1.s.v; a1=u2.s.v; a2=u3.s.v; }
      float pi = a0 + x0, pf = a1 + x1, pg = a2 + x2, po = a3 + x3;
      float ii = fsigm(pi), ff = fsigm(pf);
      float gv = ftanh(pg), oo = fsigm(po);
      float cn = ff*cst + ii*gv;
      float hn = oo*ftanh(cn);
      if (ml[b2*Sc+sp] != 0){ cst = cn; hpv = hn; }   // freeze on masked steps
      hl2[(j2>>4)*36 + (j2&15)*2 + b2] = hpv;
      if (g == 0){
        int sg = d ? (SLEN-1-stepg) : stepg;
        hs[((long)sg*64 + (bp*2+b2))*512 + d*256 + j2] = hpv;
      }
    }
    __syncthreads();                             // hl2 ready for next gemv
  }
  if (t < 512){
    int bg = bp*2 + b2;
    st_h[(d*64+bg)*256 + j2] = hpv;
    st_c[(d*64+bg)*256 + j2] = cst;
  }
}

__global__ __launch_bounds__(576) void feats_k(
    const float* __restrict__ hs, const float* __restrict__ wout,
    float* __restrict__ feats)
{
  __shared__ __align__(16) float hlds[64*512];
  __shared__ __align__(16) float wl[NTAG*512];
  const int s = blockIdx.x, t = threadIdx.x;
  for (int i = t; i < 64*512/4; i += 576)
    ((f32x4*)hlds)[i] = ((const f32x4*)(hs + (long)s*64*512))[i];
  for (int i = t; i < NTAG*512/4; i += 576)
    ((f32x4*)wl)[i] = ((const f32x4*)wout)[i];
  __syncthreads();
  int b = t / 9, tag = t - b*9;
  float acc = 0.f;
  const float* hb = hlds + b*512;
  const float* wb = wl + tag*512;
  for (int k=0; k<512; k+=4){
    f32x4 h4 = *(const f32x4*)(hb+k);
    f32x4 w4 = *(const f32x4*)(wb+k);
    acc += h4.x*w4.x + h4.y*w4.y + h4.z*w4.z + h4.w*w4.w;
  }
  feats[((long)s*64 + b)*9 + tag] = acc;
}

__global__ __launch_bounds__(64) void viterbi_k(
    const int* __restrict__ ids, const float* __restrict__ feats,
    const float* __restrict__ bout, const float* __restrict__ trans,
    int* __restrict__ outp)
{
  __shared__ float fl[SLEN*NTAG + 64];
  __shared__ unsigned char bps[SLEN*NTAG];
  __shared__ unsigned char mk[SLEN];
  const int b = blockIdx.x, lane = threadIdx.x;
  for (int i=lane; i<SLEN; i+=64) mk[i] = (ids[b*SLEN+i] != 0) ? 1 : 0;
  for (int i=lane; i<SLEN*NTAG; i+=64){
    int s = i/9; int t = i - s*9;
    fl[i] = feats[((long)s*64+b)*9 + t] + bout[t];
  }
  fl[SLEN*NTAG + lane] = 0.f;
  __syncthreads();

  float Tc[9], v[9], vown;
  #pragma unroll
  for (int i=0;i<9;i++) Tc[i] = (lane<9)? trans[i*9 + lane] : 0.f;
  #pragma unroll
  for (int i=0;i<9;i++) v[i] = (i==0)?0.f:NEGV;
  vown = (lane==0)?0.f:NEGV;

  for (int s=0;s<SLEN;s++){
    float best = v[0] + Tc[0]; int bi = 0;
    #pragma unroll
    for (int i=1;i<9;i++){
      float sc = v[i] + Tc[i];
      if (sc > best){ best = sc; bi = i; }       // first-max tie-break
    }
    float nv = best + fl[s*9 + lane];
    bool m = mk[s] != 0;
    if (m && lane<9) vown = nv;
    if (lane < 9) bps[s*9+lane] = (unsigned char)bi;
    #pragma unroll
    for (int i=0;i<9;i++) v[i] = __shfl(vown, i);
  }
  if (lane == 0){
    float best = v[0]; int tag = 0;
    #pragma unroll
    for (int i=1;i<9;i++) if (v[i] > best){ best=v[i]; tag=i; }
    outp[b*SLEN + SLEN-1] = tag;
    for (int t=SLEN-1; t>=1; t--){
      int pv = bps[t*9 + tag];
      if (!mk[t]) pv = 0;
      outp[b*SLEN + t-1] = pv;
      tag = pv;
    }
  }
}

extern "C" void kernel_launch(void* const* d_in, const int* in_sizes, int n_in,
                              void* d_out, int out_size, void* d_ws, size_t ws_size,
                              hipStream_t stream){
  (void)in_sizes; (void)n_in; (void)out_size;
  const int*   ids   = (const int*)  d_in[0];
  const float* embed = (const float*)d_in[2];
  const float* Wih_f = (const float*)d_in[3];
  const float* Whh_f = (const float*)d_in[4];
  const float* b_f   = (const float*)d_in[5];
  const float* Wih_r = (const float*)d_in[6];
  const float* Whh_r = (const float*)d_in[7];
  const float* b_r   = (const float*)d_in[8];
  const float* Wout  = (const float*)d_in[9];
  const float* bout  = (const float*)d_in[10];
  const float* trans = (const float*)d_in[11];

  float* fw = (float*)d_ws;
  size_t off = 0;
  float* wS    = fw + off; off += 1048576;     // 4 MB swizzled Wih+Whh
  unsigned long long* send = (unsigned long long*)(fw + off); off += 524288; // 2 MB tagged
  float* st_h  = fw + off; off += 32768;
  float* st_c  = fw + off; off += 32768;
  float* hs    = fw + off; off += 16777216;    // 64 MB [512][64][512]
  float* featb = fw + off; off += 294912;      // [512][64][9]
  float* xg    = fw + off;
  size_t fixedB = off*4;

  const int cands[7] = {512,256,128,64,32,16,8};
  int Sc = 8;
  for (int ci=0; ci<7; ci++){
    size_t need = fixedB + (size_t)cands[ci]*262144*4;  // xg = 2par*2d*Sc*64*1024 f32
    if (need <= ws_size){ Sc = cands[ci]; break; }
  }
  const long xg_par_str = (long)Sc*131072;
  const int C = SLEN / Sc;

  hipMemsetAsync(send, 0, 524288*4, stream);   // tags must not survive replays
  hipMemsetAsync(st_h, 0, 2*32768*4, stream);  // st_h + st_c contiguous
  prep_k<<<1024,256,0,stream>>>(Wih_f, Whh_f, Wih_r, Whh_r, wS);
  for (int c0=0; c0<C; c0++){
    xproj_k<<<256,1024,0,stream>>>(c0, Sc, ids, embed, wS, b_f, b_r, xg, xg_par_str);
    recur_k<<<256,1024,0,stream>>>(c0, Sc, ids, wS, xg, xg_par_str, hs, st_h, st_c, send);
  }
  feats_k<<<512,576,0,stream>>>(hs, Wout, featb);
  viterbi_k<<<64,64,0,stream>>>(ids, featb, bout, trans, (int*)d_out);
}

// Round 15
// 1840.941 us; speedup vs baseline: 1.3197x; 1.0003x over previous
//
#include <hip/hip_runtime.h>

// BiLSTM-CRF, f32-faithful.
// R15 = R14 + lgkm-only barriers in recur/xproj. HIP __syncthreads emits
// s_waitcnt vmcnt(0) before s_barrier, which stalls every step on the IC
// write-ack of our own sends (and the hs store). The tagged-data protocol
// doesn't need it: tag+value are one 8B atomic (release carried by the
// atom), same-address resends are HW-ordered across the distance-2 parity
// reuse. Only LDS handoffs need lgkmcnt(0). Everything else = R14
// (R9 recur geometry + fast transcendentals + bulk-staged xproj).

#define SLEN 512
#define NTAG 9
#define NEGV -10000.0f

typedef float f32x2 __attribute__((ext_vector_type(2)));
typedef float f32x4 __attribute__((ext_vector_type(4)));

// barrier that drains LDS only (not vmcnt) — see header comment
#define BAR_LGKM asm volatile("s_waitcnt lgkmcnt(0)\n\ts_barrier" ::: "memory");

__device__ __forceinline__ float qsum(float v){
  int t = __builtin_amdgcn_update_dpp(0, __float_as_int(v), 0xB1, 0xF, 0xF, false);
  v += __int_as_float(t);
  t = __builtin_amdgcn_update_dpp(0, __float_as_int(v), 0x4E, 0xF, 0xF, false);
  return v + __int_as_float(t);
}
__device__ __forceinline__ float rsum16(float v){
  v = qsum(v);
  int t = __builtin_amdgcn_update_dpp(0, __float_as_int(v), 0x124, 0xF, 0xF, false);
  v += __int_as_float(t);
  t = __builtin_amdgcn_update_dpp(0, __float_as_int(v), 0x128, 0xF, 0xF, false);
  return v + __int_as_float(t);
}

// fast transcendentals: v_exp_f32 (2^x) + v_rcp_f32, ~1ulp each.
__device__ __forceinline__ float fexp2(float x){
  float r; asm("v_exp_f32 %0, %1" : "=v"(r) : "v"(x)); return r;
}
__device__ __forceinline__ float frcp(float x){
  float r; asm("v_rcp_f32 %0, %1" : "=v"(r) : "v"(x)); return r;
}
__device__ __forceinline__ float fsigm(float x){          // 1/(1+e^-x)
  return frcp(1.0f + fexp2(-1.4426950408889634f * x));
}
__device__ __forceinline__ float ftanh(float x){          // 2*sigm(2x)-1
  return fmaf(2.0f, frcp(1.0f + fexp2(-2.8853900817779268f * x)), -1.0f);
}

#define MAC2(S, WP, HV) { \
  f32x2 _h01{(HV).x,(HV).y}, _h23{(HV).z,(HV).w}; \
  asm("v_pk_fma_f32 %0, %1, %2, %0 op_sel:[0,0,0] op_sel_hi:[0,1,1]" : "+v"(S) : "v"(WP), "v"(_h01)); \
  asm("v_pk_fma_f32 %0, %1, %2, %0 op_sel:[1,0,0] op_sel_hi:[1,1,1]" : "+v"(S) : "v"(WP), "v"(_h23)); }

#define LDW(rr,kq,A,B) { f32x4 v = wp[((rr)*4+(kq))*1024 + t]; A = f32x2{v.x,v.y}; B = f32x2{v.z,v.w}; }

#define DECLW \
  f32x2 w00,w01,w02,w03,w04,w05,w06,w07; \
  f32x2 w10,w11,w12,w13,w14,w15,w16,w17; \
  f32x2 w20,w21,w22,w23,w24,w25,w26,w27; \
  f32x2 w30,w31,w32,w33,w34,w35,w36,w37; \
  LDW(0,0,w00,w01) LDW(0,1,w02,w03) LDW(0,2,w04,w05) LDW(0,3,w06,w07) \
  LDW(1,0,w10,w11) LDW(1,1,w12,w13) LDW(1,2,w14,w15) LDW(1,3,w16,w17) \
  LDW(2,0,w20,w21) LDW(2,1,w22,w23) LDW(2,2,w24,w25) LDW(2,3,w26,w27) \
  LDW(3,0,w30,w31) LDW(3,1,w32,w33) LDW(3,2,w34,w35) LDW(3,3,w36,w37)

#define PINW \
  asm volatile("" : "+v"(w00),"+v"(w01),"+v"(w02),"+v"(w03),"+v"(w04),"+v"(w05),"+v"(w06),"+v"(w07)); \
  asm volatile("" : "+v"(w10),"+v"(w11),"+v"(w12),"+v"(w13),"+v"(w14),"+v"(w15),"+v"(w16),"+v"(w17)); \
  asm volatile("" : "+v"(w20),"+v"(w21),"+v"(w22),"+v"(w23),"+v"(w24),"+v"(w25),"+v"(w26),"+v"(w27)); \
  asm volatile("" : "+v"(w30),"+v"(w31),"+v"(w32),"+v"(w33),"+v"(w34),"+v"(w35),"+v"(w36),"+v"(w37));

#define GCHUNK(c, WA0,WA1, WB0,WB1, WC0,WC1, WD0,WD1) { \
  f32x4 hA = *(const f32x4*)(hb + (c)*8); \
  f32x4 hB = *(const f32x4*)(hb + (c)*8 + 4); \
  MAC2(s0,WA0,hA) MAC2(s0,WA1,hB) \
  MAC2(s1,WB0,hA) MAC2(s1,WB1,hB) \
  MAC2(s2,WC0,hA) MAC2(s2,WC1,hB) \
  MAC2(s3,WD0,hA) MAC2(s3,WD1,hB) }

#define GEMV4x16 \
  f32x2 s0{0.f,0.f}, s1{0.f,0.f}, s2{0.f,0.f}, s3{0.f,0.f}; \
  GCHUNK(0, w00,w01, w10,w11, w20,w21, w30,w31) \
  GCHUNK(1, w02,w03, w12,w13, w22,w23, w32,w33) \
  GCHUNK(2, w04,w05, w14,w15, w24,w25, w34,w35) \
  GCHUNK(3, w06,w07, w16,w17, w26,w27, w36,w37)

union PK { struct { float v; int tg; } s; unsigned long long u; };

// wS[(((role*2+d)*4+g)*16 + rr*4+kq)*4096 + t*4 + e] =
//   W[g*256 + (t>>4)*4 + rr][(t&15)*16 + kq*4 + e]   role0=Wih, role1=Whh
__global__ void prep_k(const float* __restrict__ wihf, const float* __restrict__ whhf,
                       const float* __restrict__ wihr, const float* __restrict__ whhr,
                       float* __restrict__ wS){
  for (int i = blockIdx.x*blockDim.x + threadIdx.x; i < (1<<20); i += gridDim.x*blockDim.x){
    int e=i&3, t=(i>>2)&1023, inst=(i>>12)&15, g=(i>>16)&3, d=(i>>18)&1, role=(i>>19)&1;
    int rr = inst>>2, kq = inst&3;
    int row = g*256 + (t>>4)*4 + rr;
    int k   = (t&15)*16 + kq*4 + e;
    const float* s = role ? (d? whhr : whhf) : (d? wihr : wihf);
    wS[i] = s[row*256 + k];
  }
}

// xproj (R12 bulk-staged): block (d,g,bp). Stage SH=min(64,Sc) steps x 2
// batches of x into LDS, then barrier-free inner loop.
__global__ __launch_bounds__(1024)
__attribute__((amdgpu_waves_per_eu(4,4)))
void xproj_k(
    int c0, int Sc,
    const int* __restrict__ ids, const float* __restrict__ embed,
    const float* __restrict__ wS,
    const float* __restrict__ bias_f, const float* __restrict__ bias_r,
    float* __restrict__ xg, long xg_par_str)
{
  __shared__ __align__(16) float xbig[64][576];   // 147KB
  __shared__ int ids_l[1024];
  const int t = threadIdx.x;
  const int bid = blockIdx.x;
  const int bp = bid & 31, g = (bid>>5)&3, d = bid>>7;
  const int rg = t>>4, ks = t&15;
  const int e = ks&3, bu = (ks>>2)&1;

  const f32x4* wp = (const f32x4*)(wS + (long)((d*4+g)*16)*4096);
  DECLW
  PINW
  const float bbr = (d ? bias_r : bias_f)[g*256 + rg*4 + e];

  for (int i=t; i<2*Sc; i+=1024){
    int b = (i>=Sc) ? 1 : 0, sp = i - b*Sc;
    int sg = d ? (SLEN-1-(c0*Sc+sp)) : (c0*Sc+sp);
    ids_l[i] = ids[(bp*2+b)*SLEN + sg];
  }
  const int SH = (Sc < 64) ? Sc : 64;
  float* xgb = xg + (long)(c0&1)*xg_par_str;

  for (int sp0=0; sp0<Sc; sp0+=SH){
    BAR_LGKM                                      // prior reads (+ids writes) done
    for (int c = t; c < SH*128; c += 1024){       // c = ss*128 + b*64 + kk
      int ss = c>>7, b = (c>>6)&1, kk = c&63;
      int sp = sp0 + ss;
      f32x4 v = ((const f32x4*)embed)[(long)ids_l[b*Sc+sp]*64 + kk];
      float* xb = &xbig[ss][(kk>>2)*36 + (kk&3)*8 + b];
      xb[0] = v.x; xb[2] = v.y; xb[4] = v.z; xb[6] = v.w;
    }
    BAR_LGKM
    for (int sp=sp0; sp<sp0+SH; sp++){
      const float* hb = &xbig[sp-sp0][ks*36];
      GEMV4x16
      float r0a = rsum16(s0.x), r0b = rsum16(s0.y);
      float r1a = rsum16(s1.x), r1b = rsum16(s1.y);
      float r2a = rsum16(s2.x), r2b = rsum16(s2.y);
      float r3a = rsum16(s3.x), r3b = rsum16(s3.y);
      if (ks < 8){
        float va = (e==0)?r0a:(e==1)?r1a:(e==2)?r2a:r3a;
        float vb = (e==0)?r0b:(e==1)?r1b:(e==2)?r2b:r3b;
        long base = ((long)(d*Sc+sp)*64 + (bp*2+bu))*1024 + g*256 + rg*4 + e;
        xgb[base] = (bu ? vb : va) + bbr;
      }
    }
  }
}

// recur (R9 geometry + fast transcendentals + lgkm-only barriers)
__global__ __launch_bounds__(1024)
__attribute__((amdgpu_waves_per_eu(4,4)))
void recur_k(
    int c0, int Sc,
    const int* __restrict__ ids,
    const float* __restrict__ wS,
    const float* __restrict__ xg, long xg_par_str,
    float* __restrict__ hs,
    float* __restrict__ st_h, float* __restrict__ st_c,
    unsigned long long* __restrict__ send)
{
  __shared__ __align__(16) float hl2[576];
  __shared__ float ol[2][256];
  __shared__ int ml[1024];
  const int t = threadIdx.x;
  const int bid = blockIdx.x;
  const int g = (bid>>3)&3;
  const int grp = (bid&7) | ((bid>>5)<<3);
  const int d = grp>>5, bp = grp&31;
  const int rg = t>>4, ks = t&15;

  const f32x4* wp = (const f32x4*)(wS + (long)(((2+d)*4+g)*16)*4096);
  DECLW
  PINW

  for (int i=t; i<2*Sc; i+=1024){
    int b = (i>=Sc) ? 1 : 0, sp = i - b*Sc;
    int sg = d ? (SLEN-1-(c0*Sc+sp)) : (c0*Sc+sp);
    ml[i] = ids[(bp*2+b)*SLEN + sg];
  }
  float cst = 0.f, hpv = 0.f;
  const int j2 = t&255, b2 = t>>8;               // update mapping (t<512)
  if (t < 512){
    int bg = bp*2 + b2;
    hpv = st_h[(d*64+bg)*256 + j2];
    cst = st_c[(d*64+bg)*256 + j2];
    hl2[(j2>>4)*36 + (j2&15)*2 + b2] = hpv;
  }
  BAR_LGKM
  const float* xgb = xg + (long)(c0&1)*xg_par_str;
  const float* hb = hl2 + ks*36;
  const int g1 = (g+1)&3, g2c = (g+2)&3, g3 = (g+3)&3;

  for (int sp=0; sp<Sc; sp++){
    const int stepg = c0*Sc + sp;
    const int par = stepg & 1;
    const int target = stepg + 1;
    float x0=0,x1=0,x2=0,x3=0;
    if (t < 512){
      const float* xr = xgb + ((long)(d*Sc+sp)*64 + (bp*2+b2))*1024 + j2;
      x0 = xr[0]; x1 = xr[256]; x2 = xr[512]; x3 = xr[768];
    }
    GEMV4x16
    float r0a = rsum16(s0.x), r0b = rsum16(s0.y);
    float r1a = rsum16(s1.x), r1b = rsum16(s1.y);
    float r2a = rsum16(s2.x), r2b = rsum16(s2.y);
    float r3a = rsum16(s3.x), r3b = rsum16(s3.y);
    if (ks < 4){
      float ra = (ks==0)?r0a:(ks==1)?r1a:(ks==2)?r2a:r3a;
      float rb = (ks==0)?r0b:(ks==1)?r1b:(ks==2)?r2b:r3b;
      int j = rg*4 + ks;
      ol[0][j] = ra; ol[1][j] = rb;
      PK pa; pa.s.v = ra; pa.s.tg = target;
      PK pb; pb.s.v = rb; pb.s.tg = target;
      unsigned long long* sb = send + ((((long)(par*64+grp)*4 + g)*2)*256) + j;
      __hip_atomic_store(sb,       pa.u, __ATOMIC_RELAXED, __HIP_MEMORY_SCOPE_AGENT);
      __hip_atomic_store(sb + 256, pb.u, __ATOMIC_RELAXED, __HIP_MEMORY_SCOPE_AGENT);
    }
    BAR_LGKM                                     // ol visible; hl2 reads done (no vmcnt drain)
    if (t < 512){
      const unsigned long long* rbase =
          send + (long)(par*64+grp)*4*2*256 + b2*256 + j2;
      PK u1, u2, u3;
      u1.u = __hip_atomic_load(rbase + (long)g1*512,  __ATOMIC_RELAXED, __HIP_MEMORY_SCOPE_AGENT);
      u2.u = __hip_atomic_load(rbase + (long)g2c*512, __ATOMIC_RELAXED, __HIP_MEMORY_SCOPE_AGENT);
      u3.u = __hip_atomic_load(rbase + (long)g3*512,  __ATOMIC_RELAXED, __HIP_MEMORY_SCOPE_AGENT);
      int cnt = 0;
      while (u1.s.tg < target || u2.s.tg < target || u3.s.tg < target){
        if (u1.s.tg < target) u1.u = __hip_atomic_load(rbase + (long)g1*512,  __ATOMIC_RELAXED, __HIP_MEMORY_SCOPE_AGENT);
        if (u2.s.tg < target) u2.u = __hip_atomic_load(rbase + (long)g2c*512, __ATOMIC_RELAXED, __HIP_MEMORY_SCOPE_AGENT);
        if (u3.s.tg < target) u3.u = __hip_atomic_load(rbase + (long)g3*512,  __ATOMIC_RELAXED, __HIP_MEMORY_SCOPE_AGENT);
        if (++cnt > (1<<15)) break;
      }
      float vo = ol[b2][j2];
      float a0,a1,a2,a3;                         // gates 0..3 (uniform branch on g)
      if      (g==0){ a0=vo;     a1=u1.s.v; a2=u2.s.v; a3=u3.s.v; }
      else if (g==1){ a1=vo;     a2=u1.s.v; a3=u2.s.v; a0=u3.s.v; }
      else if (g==2){ a2=vo;     a3=u1.s.v; a0=u2.s.v; a1=u3.s.v; }
      else          { a3=vo;     a0=u1.s.v; a1=u2.s.v; a2=u3.s.v; }
      float pi = a0 + x0, pf = a1 + x1, pg = a2 + x2, po = a3 + x3;
      float ii = fsigm(pi), ff = fsigm(pf);
      float gv = ftanh(pg), oo = fsigm(po);
      float cn = ff*cst + ii*gv;
      float hn = oo*ftanh(cn);
      if (ml[b2*Sc+sp] != 0){ cst = cn; hpv = hn; }   // freeze on masked steps
      hl2[(j2>>4)*36 + (j2&15)*2 + b2] = hpv;
      if (g == 0){
        int sg = d ? (SLEN-1-stepg) : stepg;
        hs[((long)sg*64 + (bp*2+b2))*512 + d*256 + j2] = hpv;
      }
    }
    BAR_LGKM                                     // hl2 ready for next gemv
  }
  if (t < 512){
    int bg = bp*2 + b2;
    st_h[(d*64+bg)*256 + j2] = hpv;
    st_c[(d*64+bg)*256 + j2] = cst;
  }
}

__global__ __launch_bounds__(576) void feats_k(
    const float* __restrict__ hs, const float* __restrict__ wout,
    float* __restrict__ feats)
{
  __shared__ __align__(16) float hlds[64*512];
  __shared__ __align__(16) float wl[NTAG*512];
  const int s = blockIdx.x, t = threadIdx.x;
  for (int i = t; i < 64*512/4; i += 576)
    ((f32x4*)hlds)[i] = ((const f32x4*)(hs + (long)s*64*512))[i];
  for (int i = t; i < NTAG*512/4; i += 576)
    ((f32x4*)wl)[i] = ((const f32x4*)wout)[i];
  __syncthreads();
  int b = t / 9, tag = t - b*9;
  float acc = 0.f;
  const float* hb = hlds + b*512;
  const float* wb = wl + tag*512;
  for (int k=0; k<512; k+=4){
    f32x4 h4 = *(const f32x4*)(hb+k);
    f32x4 w4 = *(const f32x4*)(wb+k);
    acc += h4.x*w4.x + h4.y*w4.y + h4.z*w4.z + h4.w*w4.w;
  }
  feats[((long)s*64 + b)*9 + tag] = acc;
}

__global__ __launch_bounds__(64) void viterbi_k(
    const int* __restrict__ ids, const float* __restrict__ feats,
    const float* __restrict__ bout, const float* __restrict__ trans,
    int* __restrict__ outp)
{
  __shared__ float fl[SLEN*NTAG + 64];
  __shared__ unsigned char bps[SLEN*NTAG];
  __shared__ unsigned char mk[SLEN];
  const int b = blockIdx.x, lane = threadIdx.x;
  for (int i=lane; i<SLEN; i+=64) mk[i] = (ids[b*SLEN+i] != 0) ? 1 : 0;
  for (int i=lane; i<SLEN*NTAG; i+=64){
    int s = i/9; int t = i - s*9;
    fl[i] = feats[((long)s*64+b)*9 + t] + bout[t];
  }
  fl[SLEN*NTAG + lane] = 0.f;
  __syncthreads();

  float Tc[9], v[9], vown;
  #pragma unroll
  for (int i=0;i<9;i++) Tc[i] = (lane<9)? trans[i*9 + lane] : 0.f;
  #pragma unroll
  for (int i=0;i<9;i++) v[i] = (i==0)?0.f:NEGV;
  vown = (lane==0)?0.f:NEGV;

  for (int s=0;s<SLEN;s++){
    float best = v[0] + Tc[0]; int bi = 0;
    #pragma unroll
    for (int i=1;i<9;i++){
      float sc = v[i] + Tc[i];
      if (sc > best){ best = sc; bi = i; }       // first-max tie-break
    }
    float nv = best + fl[s*9 + lane];
    bool m = mk[s] != 0;
    if (m && lane<9) vown = nv;
    if (lane < 9) bps[s*9+lane] = (unsigned char)bi;
    #pragma unroll
    for (int i=0;i<9;i++) v[i] = __shfl(vown, i);
  }
  if (lane == 0){
    float best = v[0]; int tag = 0;
    #pragma unroll
    for (int i=1;i<9;i++) if (v[i] > best){ best=v[i]; tag=i; }
    outp[b*SLEN + SLEN-1] = tag;
    for (int t=SLEN-1; t>=1; t--){
      int pv = bps[t*9 + tag];
      if (!mk[t]) pv = 0;
      outp[b*SLEN + t-1] = pv;
      tag = pv;
    }
  }
}

extern "C" void kernel_launch(void* const* d_in, const int* in_sizes, int n_in,
                              void* d_out, int out_size, void* d_ws, size_t ws_size,
                              hipStream_t stream){
  (void)in_sizes; (void)n_in; (void)out_size;
  const int*   ids   = (const int*)  d_in[0];
  const float* embed = (const float*)d_in[2];
  const float* Wih_f = (const float*)d_in[3];
  const float* Whh_f = (const float*)d_in[4];
  const float* b_f   = (const float*)d_in[5];
  const float* Wih_r = (const float*)d_in[6];
  const float* Whh_r = (const float*)d_in[7];
  const float* b_r   = (const float*)d_in[8];
  const float* Wout  = (const float*)d_in[9];
  const float* bout  = (const float*)d_in[10];
  const float* trans = (const float*)d_in[11];

  float* fw = (float*)d_ws;
  size_t off = 0;
  float* wS    = fw + off; off += 1048576;     // 4 MB swizzled Wih+Whh
  unsigned long long* send = (unsigned long long*)(fw + off); off += 524288; // 2 MB tagged
  float* st_h  = fw + off; off += 32768;
  float* st_c  = fw + off; off += 32768;
  float* hs    = fw + off; off += 16777216;    // 64 MB [512][64][512]
  float* featb = fw + off; off += 294912;      // [512][64][9]
  float* xg    = fw + off;
  size_t fixedB = off*4;

  const int cands[7] = {512,256,128,64,32,16,8};
  int Sc = 8;
  for (int ci=0; ci<7; ci++){
    size_t need = fixedB + (size_t)cands[ci]*262144*4;  // xg = 2par*2d*Sc*64*1024 f32
    if (need <= ws_size){ Sc = cands[ci]; break; }
  }
  const long xg_par_str = (long)Sc*131072;
  const int C = SLEN / Sc;

  hipMemsetAsync(send, 0, 524288*4, stream);   // tags must not survive replays
  hipMemsetAsync(st_h, 0, 2*32768*4, stream);  // st_h + st_c contiguous
  prep_k<<<1024,256,0,stream>>>(Wih_f, Whh_f, Wih_r, Whh_r, wS);
  for (int c0=0; c0<C; c0++){
    xproj_k<<<256,1024,0,stream>>>(c0, Sc, ids, embed, wS, b_f, b_r, xg, xg_par_str);
    recur_k<<<256,1024,0,stream>>>(c0, Sc, ids, wS, xg, xg_par_str, hs, st_h, st_c, send);
  }
  feats_k<<<512,576,0,stream>>>(hs, Wout, featb);
  viterbi_k<<<64,64,0,stream>>>(ids, featb, bout, trans, (int*)d_out);
}